// Round 1
// 113.394 us; speedup vs baseline: 1.0371x; 1.0371x over previous
//
#include <hip/hip_runtime.h>

#define T_LEN      6000
#define F_DIM      80
#define NROWS      2560          // 32 * 80
#define CHUNK      256           // 64 lanes * 4 elems
#define NSEG       4             // time-segments per row; 2560*4 = 10240 waves = 40/CU demand
#define SEG_CHUNKS 6             // 6*256 = 1536 elems/segment (last segment: 1392 real + pad)
#define SEG_LEN    (SEG_CHUNKS * CHUNK)
#define WARM_CH    2             // 512-elem warm-up: c^512 ~ 8.6e-10 @ c=0.96 -> below fp32 eps
#define FLOORV     1e-6f

// gfx950 hardware transcendentals (avoid glibc __exp2f/__log2f name collision)
__device__ __forceinline__ float hw_exp2(float x) { return __builtin_amdgcn_exp2f(x); }
__device__ __forceinline__ float hw_log2(float x) { return __builtin_amdgcn_logf(x); }

__global__ __launch_bounds__(256) void pcen_kernel(
    const float* __restrict__ x,
    const float* __restrict__ smooth,
    const float* __restrict__ alpha,
    const float* __restrict__ delta,
    const float* __restrict__ root,
    float* __restrict__ out)
{
    const int lane = threadIdx.x & 63;
    const int gw   = blockIdx.x * 4 + (threadIdx.x >> 6);  // global wave id, 0..10239
    const int row  = gw >> 2;                              // 4 waves of a block share one row
    const int seg  = gw & (NSEG - 1);
    const int f    = row % F_DIM;

    // per-row parameters (wave-uniform)
    float s   = fminf(fmaxf(smooth[f], 0.f), 1.f);
    float c   = 1.f - s;
    float a   = fminf(alpha[f], 1.f);
    float d   = delta[f];
    float r   = fmaxf(root[f], 1.f);
    float inv_r = 1.f / r;
    float neg_a = -a;
    const bool use_sqrt = (inv_r == 0.5f);                 // root==2 -> y^(1/r) is v_sqrt_f32
    float droot = use_sqrt ? __builtin_amdgcn_sqrtf(d)
                           : hw_exp2(inv_r * hw_log2(d));  // d^(1/r), d > 0 per problem

    // powers of c
    const float c1 = c, c2 = c * c, c3 = c2 * c, c4 = c2 * c2;
    float q0 = c4;                 // c^4
    float q1 = q0 * q0;            // c^8
    float q2 = q1 * q1;            // c^16
    float q3 = q2 * q2;            // c^32
    float q4 = q3 * q3;            // c^64
    float q5 = q4 * q4;            // c^128
    float c256 = q5 * q5;          // c^256 : full-chunk decay
    // c^(4*lane); guard lane==0 against 0 * (-inf) when c==0
    float c4lane = (lane == 0) ? 1.0f : hw_exp2(4.0f * (float)lane * hw_log2(c));

    const float* __restrict__ px = x   + (size_t)row * T_LEN;
    float*       __restrict__ po = out + (size_t)row * T_LEN;
    const int t0 = seg * SEG_LEN;
    const int tw = t0 - WARM_CH * CHUNK;                   // >= 1024 whenever seg > 0

    // ---- issue ALL loads up-front: 2 warm-up + 6 main chunks = 8 KB/wave in flight ----
    float4 w0 = make_float4(0.f, 0.f, 0.f, 0.f), w1 = w0;
    if (seg) {
        w0 = *reinterpret_cast<const float4*>(px + tw +          lane * 4);
        w1 = *reinterpret_cast<const float4*>(px + tw + CHUNK +  lane * 4);
    }
    float4 v[SEG_CHUNKS];
#pragma unroll
    for (int k = 0; k < SEG_CHUNKS; ++k) {
        int t = t0 + k * CHUNK + lane * 4;
        v[k] = (t < T_LEN) ? *reinterpret_cast<const float4*>(px + t)
                           : make_float4(0.f, 0.f, 0.f, 0.f);
    }

    // EMA seed. seg 0: carry=x[0] makes m0 = c*x0 + s*x0 = x0 (ref: ema[0]=x[0], exact).
    // seg > 0: arbitrary seed 512 elems early; error decays by c^512 ~ 8.6e-10.
    float carry = seg ? px[tw] : px[0];

    // ---- warm-up: advance carry over 512 elems, no outputs ----
    if (seg) {
#pragma unroll
        for (int k = 0; k < WARM_CH; ++k) {
            float4 cur = (k == 0) ? w0 : w1;
            float b0 = s * cur.x;
            float b1 = fmaf(c1, b0, s * cur.y);
            float b2 = fmaf(c1, b1, s * cur.z);
            float b3 = fmaf(c1, b2, s * cur.w);
            float B = b3, Bu;
            Bu = __shfl_up(B, 1, 64);  if (lane >= 1)  B = fmaf(q0, Bu, B);
            Bu = __shfl_up(B, 2, 64);  if (lane >= 2)  B = fmaf(q1, Bu, B);
            Bu = __shfl_up(B, 4, 64);  if (lane >= 4)  B = fmaf(q2, Bu, B);
            Bu = __shfl_up(B, 8, 64);  if (lane >= 8)  B = fmaf(q3, Bu, B);
            Bu = __shfl_up(B, 16, 64); if (lane >= 16) B = fmaf(q4, Bu, B);
            Bu = __shfl_up(B, 32, 64); if (lane >= 32) B = fmaf(q5, Bu, B);
            float B63 = __shfl(B, 63, 64);
            carry = fmaf(c256, carry, B63);
        }
    }

    // ---- main: 6 chunks with pcen outputs ----
#pragma unroll
    for (int k = 0; k < SEG_CHUNKS; ++k) {
        float4 cur = v[k];

        // local (per-lane) inclusive scan of 4 elements, as if m_in = 0
        float b0 = s * cur.x;
        float b1 = fmaf(c1, b0, s * cur.y);
        float b2 = fmaf(c1, b1, s * cur.z);
        float b3 = fmaf(c1, b2, s * cur.w);

        // wave scan over lane carries (A-coefficients are the uniform scalars q_k)
        float B = b3, Bu;
        Bu = __shfl_up(B, 1, 64);  if (lane >= 1)  B = fmaf(q0, Bu, B);
        Bu = __shfl_up(B, 2, 64);  if (lane >= 2)  B = fmaf(q1, Bu, B);
        Bu = __shfl_up(B, 4, 64);  if (lane >= 4)  B = fmaf(q2, Bu, B);
        Bu = __shfl_up(B, 8, 64);  if (lane >= 8)  B = fmaf(q3, Bu, B);
        Bu = __shfl_up(B, 16, 64); if (lane >= 16) B = fmaf(q4, Bu, B);
        Bu = __shfl_up(B, 32, 64); if (lane >= 32) B = fmaf(q5, Bu, B);

        // exclusive prefix for this lane
        float Bex = __shfl_up(B, 1, 64);
        if (lane == 0) Bex = 0.f;
        float m_in = fmaf(c4lane, carry, Bex);

        // chunk carry update early so scheduler can overlap with pcen math
        float B63 = __shfl(B, 63, 64);
        carry = fmaf(c256, carry, B63);

        // per-element EMA values
        float m0 = fmaf(c1, m_in, b0);
        float m1 = fmaf(c2, m_in, b1);
        float m2 = fmaf(c3, m_in, b2);
        float m3 = fmaf(c4, m_in, b3);

        // pcen: g = (FLOOR+m)^(-a); y = x*g + d; out = y^(1/r) - d^(1/r)
        float y0 = fmaf(cur.x, hw_exp2(neg_a * hw_log2(m0 + FLOORV)), d);
        float y1 = fmaf(cur.y, hw_exp2(neg_a * hw_log2(m1 + FLOORV)), d);
        float y2 = fmaf(cur.z, hw_exp2(neg_a * hw_log2(m2 + FLOORV)), d);
        float y3 = fmaf(cur.w, hw_exp2(neg_a * hw_log2(m3 + FLOORV)), d);

        float4 o;
        if (use_sqrt) {            // wave-uniform branch: single v_sqrt_f32 per element
            o.x = __builtin_amdgcn_sqrtf(y0) - droot;
            o.y = __builtin_amdgcn_sqrtf(y1) - droot;
            o.z = __builtin_amdgcn_sqrtf(y2) - droot;
            o.w = __builtin_amdgcn_sqrtf(y3) - droot;
        } else {
            o.x = hw_exp2(inv_r * hw_log2(y0)) - droot;
            o.y = hw_exp2(inv_r * hw_log2(y1)) - droot;
            o.z = hw_exp2(inv_r * hw_log2(y2)) - droot;
            o.w = hw_exp2(inv_r * hw_log2(y3)) - droot;
        }

        int t = t0 + k * CHUNK + lane * 4;
        if (t < T_LEN) {
            *reinterpret_cast<float4*>(po + t) = o;
        }
    }
}

extern "C" void kernel_launch(void* const* d_in, const int* in_sizes, int n_in,
                              void* d_out, int out_size, void* d_ws, size_t ws_size,
                              hipStream_t stream) {
    const float* x      = (const float*)d_in[0];
    const float* smooth = (const float*)d_in[1];
    const float* alpha  = (const float*)d_in[2];
    const float* delta  = (const float*)d_in[3];
    const float* root   = (const float*)d_in[4];
    float* out = (float*)d_out;

    // 2560 rows * 4 time-segments = 10240 waves; 4 waves/block (one row per block)
    dim3 grid(NROWS * NSEG / 4);   // 2560 blocks
    dim3 block(256);
    pcen_kernel<<<grid, block, 0, stream>>>(x, smooth, alpha, delta, root, out);
}